// Round 15
// baseline (91.217 us; speedup 1.0000x reference)
//
#include <hip/hip_runtime.h>
#include <hip/hip_fp16.h>

#define BATCH 8
#define NPTS  4096
#define NPER  32768          // BATCH*NPTS per cloud
#define NQTOT (2 * NPER)
#define WROWS 32             // query rows per wave
#define BROWS 128            // rows per block (4 waves)
#define MTILES (NPTS / 32)   // 128 target tiles of 32

typedef _Float16 half8  __attribute__((ext_vector_type(8)));
typedef float    f32x16 __attribute__((ext_vector_type(16)));

// ws layout:
//   ushort4 pkh[65536] : f16-rounded coords (hx,hy,hz,0); pred then gt (512 KB)
//   float   n2[65536]  : |p~|^2 in fp32 computed FROM the rounded coords (256 KB)

// K0: round coords to f16 once; chamfer of the perturbed config is computed
// exactly from here on (coord err ~5e-4 -> final err ~1e-3 << 6.25e-3).
__global__ __launch_bounds__(256) void pack_kernel(
    const float* __restrict__ pred, const float* __restrict__ gt,
    ushort4* __restrict__ pkh, float* __restrict__ n2)
{
    const int j = blockIdx.x * 256 + threadIdx.x;     // 0..65535
    const float* src = (j < NPER) ? pred : gt;
    const float* p = src + (size_t)(j & (NPER - 1)) * 3;
    const __half hx = __float2half(p[0]);
    const __half hy = __float2half(p[1]);
    const __half hz = __float2half(p[2]);
    ushort4 u;
    u.x = __half_as_ushort(hx);
    u.y = __half_as_ushort(hy);
    u.z = __half_as_ushort(hz);
    u.w = 0;
    pkh[j] = u;
    const float fx = __half2float(hx), fy = __half2float(hy), fz = __half2float(hz);
    n2[j] = fmaf(fx, fx, fmaf(fy, fy, fz * fz));
}

// K1: grid (32, 1, 16) = 512 blocks x 256 thr (4 waves). Wave owns 32 query
// rows; A-frag = (-x,-y,-z,0,...) for row lane&31 (both lane-halves filled ->
// the 6 occupied k-slots give exactly -2 p.g regardless of the j->k mapping).
// Loop over 128 target tiles: B-frag = coords of target col lane&31,
// C = splat(g2[col]) in fp32 -> D = g2 - 2 p.g per (row,col).
// rowacc = elementwise min over tiles (1 v_min per pair). End: 5-step
// shfl-xor min across cols, + p2[row], clamp, sqrt, wave-sum, one atomicAdd.
__global__ __launch_bounds__(256) void chamfer_mfma_kernel(
    const ushort4* __restrict__ pkh, const float* __restrict__ n2,
    float* __restrict__ out)
{
    const int z    = blockIdx.z;                      // pass*8 + b
    const int b    = z & 7;
    const int pass = z >> 3;
    const int qoff = (pass ? NPER : 0) + b * NPTS;    // query cloud
    const int toff = (pass ? 0 : NPER) + b * NPTS;    // target cloud

    const int lane  = threadIdx.x & 63;
    const int wave  = threadIdx.x >> 6;
    const int strip = blockIdx.x * BROWS + wave * WROWS;
    const int l31   = lane & 31;

    // A fragment: negated f16 coords of query row (strip + l31), both halves.
    union { half8 h; unsigned int u[4]; } A;
    {
        const ushort4 q = pkh[qoff + strip + l31];
        A.u[0] = ((unsigned)q.x | ((unsigned)q.y << 16)) ^ 0x80008000u;
        A.u[1] = ((unsigned)q.z) ^ 0x00008000u;       // (-z, +0)
        A.u[2] = 0u;
        A.u[3] = 0u;
    }

    f32x16 racc;
#pragma unroll
    for (int i = 0; i < 16; ++i) racc[i] = 3.0e38f;

    // 1-deep software pipeline on the target-tile loads (L2-hot).
    ushort4 tb = pkh[toff + l31];
    float   g2 = n2[toff + l31];

    for (int mt = 0; mt < MTILES; ++mt) {
        const int nidx = ((mt + 1) & (MTILES - 1)) * 32 + l31;
        const ushort4 tbn = pkh[toff + nidx];         // prefetch next tile
        const float   g2n = n2[toff + nidx];

        union { half8 h; unsigned int u[4]; } B;
        B.u[0] = (unsigned)tb.x | ((unsigned)tb.y << 16);
        B.u[1] = (unsigned)tb.z;
        B.u[2] = 0u;
        B.u[3] = 0u;

        f32x16 c;
#pragma unroll
        for (int i = 0; i < 16; ++i) c[i] = g2;       // fp32 g2[col] via C-in

        const f32x16 d = __builtin_amdgcn_mfma_f32_32x32x16_f16(A.h, B.h, c, 0, 0, 0);

#pragma unroll
        for (int i = 0; i < 16; ++i) racc[i] = fminf(racc[i], d[i]);

        tb = tbn; g2 = g2n;
    }

    // Min across the 32 columns (lanes with same lane>>5 hold distinct cols).
#pragma unroll
    for (int i = 0; i < 16; ++i) {
        float v = racc[i];
        v = fminf(v, __shfl_xor(v, 1));
        v = fminf(v, __shfl_xor(v, 2));
        v = fminf(v, __shfl_xor(v, 4));
        v = fminf(v, __shfl_xor(v, 8));
        v = fminf(v, __shfl_xor(v, 16));
        racc[i] = v;
    }

    // Canonical lanes 0 and 32 hold complementary 16 rows each.
    float wsum = 0.0f;
    if (l31 == 0) {
#pragma unroll
        for (int i = 0; i < 16; ++i) {
            const int row = (i & 3) + 8 * (i >> 2) + 4 * (lane >> 5);
            const float p2 = n2[qoff + strip + row];
            const float d2 = fmaxf(racc[i] + p2, 0.0f);
            wsum += sqrtf(d2);
        }
    }
    wsum += __shfl(wsum, lane ^ 32);
    if (lane == 0) atomicAdd(out, wsum * (1.0f / (float)NPER));
}

extern "C" void kernel_launch(void* const* d_in, const int* in_sizes, int n_in,
                              void* d_out, int out_size, void* d_ws, size_t ws_size,
                              hipStream_t stream) {
    const float* pred = (const float*)d_in[0];
    const float* gt   = (const float*)d_in[1];

    ushort4* pkh = (ushort4*)d_ws;                    // 512 KB
    float*   n2  = (float*)(pkh + NQTOT);             // 256 KB

    hipMemsetAsync(d_out, 0, sizeof(float), stream);

    pack_kernel<<<NQTOT / 256, 256, 0, stream>>>(pred, gt, pkh, n2);

    dim3 grid(NPTS / BROWS, 1, 2 * BATCH);
    chamfer_mfma_kernel<<<grid, 256, 0, stream>>>(pkh, n2, (float*)d_out);
}

// Round 16
// 34.128 us; speedup vs baseline: 2.6728x; 2.6728x over previous
//
#include <hip/hip_runtime.h>
#include <hip/hip_fp16.h>

#define BATCH 8
#define NPTS  4096
#define NPER  32768          // BATCH*NPTS per cloud
#define WROWS 16             // query rows per wave (MFMA M)
#define WAVES 4
#define BROWS (WROWS * WAVES) // 64 rows per block
#define TILES (NPTS / 16)     // 256 target tiles of 16

typedef _Float16 half8 __attribute__((ext_vector_type(8)));
typedef float    f32x4 __attribute__((ext_vector_type(4)));

// Single fused kernel. grid (64, 1, 16) = 1024 blocks x 256 thr (4 waves).
// Math per (query p, target g), all from f16-rounded coords (validated R15):
//   score = g2 - 2 p.g  computed by ONE mfma_f32_16x16x32_f16 per 16x16 tile:
//   A(row) = (-2x,-2y,-2z, 1, 0...), B(col) = (x, y, z, f16(g2), 0...), C = 0.
//   d2 = max(score + p2, 0); dist = sqrt(d2); chamfer = mean over both passes.
// Block stages ALL 4096 targets of its (pass,batch) in LDS as packed uint2
// (x|y, z|g2h). Inner loop per tile: 1 ds_read_b64 (broadcast, conflict-free)
// + 1 MFMA + 4 v_min. Epilogue: shfl col-min, +p2, sqrt, wave/block sum,
// one atomicAdd per block.
__global__ __launch_bounds__(256) void chamfer_mfma_kernel(
    const float* __restrict__ pred, const float* __restrict__ gt,
    float* __restrict__ out)
{
    const int z    = blockIdx.z;                  // pass*8 + b
    const int b    = z & 7;
    const int pass = z >> 3;
    const float* query  = (pass ? gt : pred) + (size_t)b * NPTS * 3;
    const float* target = (pass ? pred : gt) + (size_t)b * NPTS * 3;

    __shared__ uint2 sT[NPTS];                    // 32 KB packed targets
    __shared__ float swsum[WAVES];

    const int tid = threadIdx.x;

    // ---- stage + convert targets (coalesced-ish, 16 per thread) ----
#pragma unroll
    for (int i = 0; i < NPTS / 256; ++i) {
        const int t = tid + i * 256;
        const float* tp = target + (size_t)t * 3;
        const __half hx = __float2half(tp[0]);
        const __half hy = __float2half(tp[1]);
        const __half hz = __float2half(tp[2]);
        const float fx = __half2float(hx), fy = __half2float(hy), fz = __half2float(hz);
        const __half hg = __float2half(fmaf(fx, fx, fmaf(fy, fy, fz * fz)));
        uint2 u;
        u.x = (unsigned)__half_as_ushort(hx) | ((unsigned)__half_as_ushort(hy) << 16);
        u.y = (unsigned)__half_as_ushort(hz) | ((unsigned)__half_as_ushort(hg) << 16);
        sT[t] = u;
    }

    const int lane = tid & 63;
    const int wave = tid >> 6;
    const int l15  = lane & 15;
    const int grp  = lane >> 4;
    const int qrow0 = blockIdx.x * BROWS + wave * WROWS;

    // ---- A fragment + query p2 (group-0 lanes own row l15) ----
    union { half8 h; unsigned u[4]; } A;
    A.u[0] = 0; A.u[1] = 0; A.u[2] = 0; A.u[3] = 0;
    float p2 = 0.0f;
    if (grp == 0) {
        const float* qp = query + (size_t)(qrow0 + l15) * 3;
        const __half hx = __float2half(qp[0]);
        const __half hy = __float2half(qp[1]);
        const __half hz = __float2half(qp[2]);
        const float fx = __half2float(hx), fy = __half2float(hy), fz = __half2float(hz);
        p2 = fmaf(fx, fx, fmaf(fy, fy, fz * fz));
        const __half ax = __float2half(-2.0f * fx);   // exact (f16 in, x2 exp)
        const __half ay = __float2half(-2.0f * fy);
        const __half az = __float2half(-2.0f * fz);
        A.u[0] = (unsigned)__half_as_ushort(ax) | ((unsigned)__half_as_ushort(ay) << 16);
        A.u[1] = (unsigned)__half_as_ushort(az) | (0x3C00u << 16);  // (-2z, 1.0)
    }
    __syncthreads();

    // ---- main loop: 256 tiles, 1-deep LDS prefetch ----
    f32x4 racc = {3.0e38f, 3.0e38f, 3.0e38f, 3.0e38f};
    const f32x4 czero = {0.0f, 0.0f, 0.0f, 0.0f};

    uint2 cur = sT[l15];
#pragma unroll 4
    for (int mt = 0; mt < TILES; ++mt) {
        const uint2 nxt = sT[((mt + 1) & (TILES - 1)) * 16 + l15];
        union { half8 h; unsigned u[4]; } B;
        B.u[0] = cur.x; B.u[1] = cur.y; B.u[2] = 0; B.u[3] = 0;
        const f32x4 d = __builtin_amdgcn_mfma_f32_16x16x32_f16(A.h, B.h, czero, 0, 0, 0);
        racc[0] = fminf(racc[0], d[0]);
        racc[1] = fminf(racc[1], d[1]);
        racc[2] = fminf(racc[2], d[2]);
        racc[3] = fminf(racc[3], d[3]);
        cur = nxt;
    }

    // ---- min over the 16 columns (within each 16-lane group) ----
#pragma unroll
    for (int i = 0; i < 4; ++i) {
        float v = racc[i];
        v = fminf(v, __shfl_xor(v, 1));
        v = fminf(v, __shfl_xor(v, 2));
        v = fminf(v, __shfl_xor(v, 4));
        v = fminf(v, __shfl_xor(v, 8));
        racc[i] = v;
    }

    // D rows of this lane-group: 4*grp + i ; p2 lives on group-0 lane 4*grp+i.
    const float p2a = __shfl(p2, 4 * grp + 0);
    const float p2b = __shfl(p2, 4 * grp + 1);
    const float p2c = __shfl(p2, 4 * grp + 2);
    const float p2d = __shfl(p2, 4 * grp + 3);

    float wsum = 0.0f;
    if (l15 == 0) {
        wsum  = sqrtf(fmaxf(racc[0] + p2a, 0.0f));
        wsum += sqrtf(fmaxf(racc[1] + p2b, 0.0f));
        wsum += sqrtf(fmaxf(racc[2] + p2c, 0.0f));
        wsum += sqrtf(fmaxf(racc[3] + p2d, 0.0f));
    }
    wsum += __shfl_xor(wsum, 16);
    wsum += __shfl_xor(wsum, 32);
    if (lane == 0) swsum[wave] = wsum;
    __syncthreads();

    if (tid == 0) {
        const float total = swsum[0] + swsum[1] + swsum[2] + swsum[3];
        atomicAdd(out, total * (1.0f / (float)NPER));
    }
}

extern "C" void kernel_launch(void* const* d_in, const int* in_sizes, int n_in,
                              void* d_out, int out_size, void* d_ws, size_t ws_size,
                              hipStream_t stream) {
    const float* pred = (const float*)d_in[0];
    const float* gt   = (const float*)d_in[1];

    hipMemsetAsync(d_out, 0, sizeof(float), stream);

    dim3 grid(NPTS / BROWS, 1, 2 * BATCH);
    chamfer_mfma_kernel<<<grid, 256, 0, stream>>>(pred, gt, (float*)d_out);
}

// Round 17
// 30.908 us; speedup vs baseline: 2.9512x; 1.1042x over previous
//
#include <hip/hip_runtime.h>
#include <hip/hip_fp16.h>

#define BATCH 8
#define NPTS  4096
#define NPER  32768           // BATCH*NPTS per cloud
#define WROWS 32              // query rows per wave (MFMA M)
#define WAVES 4
#define BROWS (WROWS * WAVES) // 128 rows per block
#define TILES (NPTS / 32)     // 128 target tiles of 32

typedef _Float16 half8  __attribute__((ext_vector_type(8)));
typedef float    f32x16 __attribute__((ext_vector_type(16)));

// Single fused kernel. grid (32, 1, 16) = 512 blocks x 256 thr (4 waves).
// Per (query p, target g), from f16-rounded coords (validated R15/R16):
//   score = g2 - 2 p.g  via one mfma_f32_32x32x16_f16 per 32x32 tile:
//   A(row) = (-2x,-2y,-2z, 1, 0...) on lanes<32 (lanes>=32 zeroed),
//   B(col) = (x, y, z, f16(g2), 0...) on lanes<32, C = 0.
//   (R15's passing run proved lane-halves carry disjoint k-slots and A/B
//    j->k maps pair up, so the 4 payload slots contract correctly.)
// Two tiles in flight per iteration -> MFMA latency hidden by the other
// tile's v_min chain. d2 = max(score + p2, 0); chamfer = mean of sqrt.
__global__ __launch_bounds__(256) void chamfer_mfma_kernel(
    const float* __restrict__ pred, const float* __restrict__ gt,
    float* __restrict__ out)
{
    const int z    = blockIdx.z;                  // pass*8 + b
    const int b    = z & 7;
    const int pass = z >> 3;
    const float* query  = (pass ? gt : pred) + (size_t)b * NPTS * 3;
    const float* target = (pass ? pred : gt) + (size_t)b * NPTS * 3;

    __shared__ uint2 sT[NPTS];                    // 32 KB packed targets
    __shared__ float swsum[WAVES];

    const int tid = threadIdx.x;

    // ---- stage + convert targets (16 per thread) ----
#pragma unroll
    for (int i = 0; i < NPTS / 256; ++i) {
        const int t = tid + i * 256;
        const float* tp = target + (size_t)t * 3;
        const __half hx = __float2half(tp[0]);
        const __half hy = __float2half(tp[1]);
        const __half hz = __float2half(tp[2]);
        const float fx = __half2float(hx), fy = __half2float(hy), fz = __half2float(hz);
        const __half hg = __float2half(fmaf(fx, fx, fmaf(fy, fy, fz * fz)));
        uint2 u;
        u.x = (unsigned)__half_as_ushort(hx) | ((unsigned)__half_as_ushort(hy) << 16);
        u.y = (unsigned)__half_as_ushort(hz) | ((unsigned)__half_as_ushort(hg) << 16);
        sT[t] = u;
    }

    const int lane = tid & 63;
    const int wave = tid >> 6;
    const int l31  = lane & 31;
    const int qrow0 = blockIdx.x * BROWS + wave * WROWS;
    const unsigned bm = (lane < 32) ? 0xFFFFFFFFu : 0u;   // low-half mask

    // ---- A fragment (+ per-lane p2 for query row l31) ----
    union { half8 h; unsigned u[4]; } A;
    A.u[2] = 0; A.u[3] = 0;
    float p2;
    {
        const float* qp = query + (size_t)(qrow0 + l31) * 3;
        const __half hx = __float2half(qp[0]);
        const __half hy = __float2half(qp[1]);
        const __half hz = __float2half(qp[2]);
        const float fx = __half2float(hx), fy = __half2float(hy), fz = __half2float(hz);
        p2 = fmaf(fx, fx, fmaf(fy, fy, fz * fz));
        const __half ax = __float2half(-2.0f * fx);   // exact (f16 in, x2 exp)
        const __half ay = __float2half(-2.0f * fy);
        const __half az = __float2half(-2.0f * fz);
        A.u[0] = ((unsigned)__half_as_ushort(ax) | ((unsigned)__half_as_ushort(ay) << 16)) & bm;
        A.u[1] = ((unsigned)__half_as_ushort(az) | (0x3C00u << 16)) & bm;  // (-2z, 1.0)
    }
    __syncthreads();

    // ---- main loop: 128 tiles of 32 targets, 2 tiles in flight ----
    f32x16 racc0, racc1, cz;
#pragma unroll
    for (int i = 0; i < 16; ++i) { racc0[i] = 3.0e38f; racc1[i] = 3.0e38f; cz[i] = 0.0f; }

#pragma unroll 2
    for (int mt = 0; mt < TILES; mt += 2) {
        const uint2 c0 = sT[mt * 32 + l31];
        const uint2 c1 = sT[mt * 32 + 32 + l31];
        union { half8 h; unsigned u[4]; } B0, B1;
        B0.u[0] = c0.x & bm; B0.u[1] = c0.y & bm; B0.u[2] = 0; B0.u[3] = 0;
        B1.u[0] = c1.x & bm; B1.u[1] = c1.y & bm; B1.u[2] = 0; B1.u[3] = 0;
        const f32x16 d0 = __builtin_amdgcn_mfma_f32_32x32x16_f16(A.h, B0.h, cz, 0, 0, 0);
        const f32x16 d1 = __builtin_amdgcn_mfma_f32_32x32x16_f16(A.h, B1.h, cz, 0, 0, 0);
#pragma unroll
        for (int i = 0; i < 16; ++i) {
            racc0[i] = fminf(racc0[i], d0[i]);
            racc1[i] = fminf(racc1[i], d1[i]);
        }
    }
#pragma unroll
    for (int i = 0; i < 16; ++i) racc0[i] = fminf(racc0[i], racc1[i]);

    // ---- min over 32 columns (shfl_xor stays within each 32-lane half) ----
#pragma unroll
    for (int i = 0; i < 16; ++i) {
        float v = racc0[i];
        v = fminf(v, __shfl_xor(v, 1));
        v = fminf(v, __shfl_xor(v, 2));
        v = fminf(v, __shfl_xor(v, 4));
        v = fminf(v, __shfl_xor(v, 8));
        v = fminf(v, __shfl_xor(v, 16));
        racc0[i] = v;
    }

    // Rows: (i&3)+8*(i>>2)+4*(lane>>5); canonical lanes 0 and 32 hold 16 each.
    float wsum = 0.0f;
#pragma unroll
    for (int i = 0; i < 16; ++i) {
        const int row = (i & 3) + 8 * (i >> 2) + 4 * (lane >> 5);  // < 32
        const float p2r = __shfl(p2, row);        // p2[lane r] = row r's |q|^2
        if (l31 == 0) wsum += sqrtf(fmaxf(racc0[i] + p2r, 0.0f));
    }
    wsum += __shfl_xor(wsum, 32);                 // combine lanes 0 and 32
    if (lane == 0) swsum[wave] = wsum;
    __syncthreads();

    if (tid == 0) {
        atomicAdd(out, (swsum[0] + swsum[1] + swsum[2] + swsum[3])
                       * (1.0f / (float)NPER));
    }
}

extern "C" void kernel_launch(void* const* d_in, const int* in_sizes, int n_in,
                              void* d_out, int out_size, void* d_ws, size_t ws_size,
                              hipStream_t stream) {
    const float* pred = (const float*)d_in[0];
    const float* gt   = (const float*)d_in[1];

    hipMemsetAsync(d_out, 0, sizeof(float), stream);

    dim3 grid(NPTS / BROWS, 1, 2 * BATCH);
    chamfer_mfma_kernel<<<grid, 256, 0, stream>>>(pred, gt, (float*)d_out);
}

// Round 18
// 25.835 us; speedup vs baseline: 3.5308x; 1.1964x over previous
//
#include <hip/hip_runtime.h>
#include <hip/hip_fp16.h>

#define BATCH 8
#define NPTS  4096
#define NPER  32768           // BATCH*NPTS per cloud
#define WROWS 32              // query rows per wave (MFMA M)
#define WAVES 8
#define BLOCK (WAVES * 64)    // 512 threads
#define BROWS (WROWS * WAVES) // 256 rows per block
#define TILES (NPTS / 32)     // 128 target tiles of 32

typedef _Float16 half8  __attribute__((ext_vector_type(8)));
typedef float    f32x16 __attribute__((ext_vector_type(16)));

// Single fused kernel. grid (16, 1, 16) = 256 blocks x 512 thr (8 waves).
// Per (query p, target g), from f16-rounded coords (validated R15-R17):
//   score = g2 - 2 p.g  via one mfma_f32_32x32x16_f16 per 32x32 tile:
//   A(row) = (-2x,-2y,-2z, 1, 0...) on lanes<32, ZERO on lanes>=32
//   (=> k=8..15 contribute 0 regardless of B's high-lane content, so B needs
//   NO masking in the loop), B(col) = raw packed (x,y,z,g2h), C = 0.
// 2 tiles in flight + 1-iter-ahead LDS prefetch. d2 = max(score+p2, 0).
__global__ __launch_bounds__(BLOCK) void chamfer_mfma_kernel(
    const float* __restrict__ pred, const float* __restrict__ gt,
    float* __restrict__ out)
{
    const int z    = blockIdx.z;                  // pass*8 + b
    const int b    = z & 7;
    const int pass = z >> 3;
    const float* query  = (pass ? gt : pred) + (size_t)b * NPTS * 3;
    const float* target = (pass ? pred : gt) + (size_t)b * NPTS * 3;

    __shared__ uint2 sT[NPTS];                    // 32 KB packed targets
    __shared__ float swsum[WAVES];

    const int tid = threadIdx.x;

    // ---- stage + convert targets (8 per thread) ----
#pragma unroll
    for (int i = 0; i < NPTS / BLOCK; ++i) {
        const int t = tid + i * BLOCK;
        const float* tp = target + (size_t)t * 3;
        const __half hx = __float2half(tp[0]);
        const __half hy = __float2half(tp[1]);
        const __half hz = __float2half(tp[2]);
        const float fx = __half2float(hx), fy = __half2float(hy), fz = __half2float(hz);
        const __half hg = __float2half(fmaf(fx, fx, fmaf(fy, fy, fz * fz)));
        uint2 u;
        u.x = (unsigned)__half_as_ushort(hx) | ((unsigned)__half_as_ushort(hy) << 16);
        u.y = (unsigned)__half_as_ushort(hz) | ((unsigned)__half_as_ushort(hg) << 16);
        sT[t] = u;
    }

    const int lane = tid & 63;
    const int wave = tid >> 6;
    const int l31  = lane & 31;
    const int qrow0 = blockIdx.x * BROWS + wave * WROWS;
    const unsigned bm = (lane < 32) ? 0xFFFFFFFFu : 0u;   // low-half mask

    // ---- A fragment (+ per-lane p2 for query row l31) ----
    union { half8 h; unsigned u[4]; } A;
    A.u[2] = 0; A.u[3] = 0;
    float p2;
    {
        const float* qp = query + (size_t)(qrow0 + l31) * 3;
        const __half hx = __float2half(qp[0]);
        const __half hy = __float2half(qp[1]);
        const __half hz = __float2half(qp[2]);
        const float fx = __half2float(hx), fy = __half2float(hy), fz = __half2float(hz);
        p2 = fmaf(fx, fx, fmaf(fy, fy, fz * fz));
        const __half ax = __float2half(-2.0f * fx);   // exact (f16 in, x2 exp)
        const __half ay = __float2half(-2.0f * fy);
        const __half az = __float2half(-2.0f * fz);
        A.u[0] = ((unsigned)__half_as_ushort(ax) | ((unsigned)__half_as_ushort(ay) << 16)) & bm;
        A.u[1] = ((unsigned)__half_as_ushort(az) | (0x3C00u << 16)) & bm;  // (-2z, 1.0)
    }
    __syncthreads();

    // ---- main loop: 128 tiles of 32 targets, 2 in flight, prefetch 1 ahead ----
    f32x16 racc0, racc1, cz;
#pragma unroll
    for (int i = 0; i < 16; ++i) { racc0[i] = 3.0e38f; racc1[i] = 3.0e38f; cz[i] = 0.0f; }

    uint2 c0 = sT[l31];
    uint2 c1 = sT[32 + l31];
#pragma unroll 2
    for (int mt = 0; mt < TILES; mt += 2) {
        const int nx = (mt + 2) & (TILES - 1);
        const uint2 n0 = sT[nx * 32 + l31];           // prefetch next iter
        const uint2 n1 = sT[nx * 32 + 32 + l31];

        union { half8 h; unsigned u[4]; } B0, B1;     // raw, unmasked
        B0.u[0] = c0.x; B0.u[1] = c0.y; B0.u[2] = 0; B0.u[3] = 0;
        B1.u[0] = c1.x; B1.u[1] = c1.y; B1.u[2] = 0; B1.u[3] = 0;
        const f32x16 d0 = __builtin_amdgcn_mfma_f32_32x32x16_f16(A.h, B0.h, cz, 0, 0, 0);
        const f32x16 d1 = __builtin_amdgcn_mfma_f32_32x32x16_f16(A.h, B1.h, cz, 0, 0, 0);
#pragma unroll
        for (int i = 0; i < 16; ++i) {
            racc0[i] = fminf(racc0[i], d0[i]);
            racc1[i] = fminf(racc1[i], d1[i]);
        }
        c0 = n0; c1 = n1;
    }
#pragma unroll
    for (int i = 0; i < 16; ++i) racc0[i] = fminf(racc0[i], racc1[i]);

    // ---- min over 32 columns (shfl_xor stays within each 32-lane half) ----
#pragma unroll
    for (int i = 0; i < 16; ++i) {
        float v = racc0[i];
        v = fminf(v, __shfl_xor(v, 1));
        v = fminf(v, __shfl_xor(v, 2));
        v = fminf(v, __shfl_xor(v, 4));
        v = fminf(v, __shfl_xor(v, 8));
        v = fminf(v, __shfl_xor(v, 16));
        racc0[i] = v;
    }

    // Rows: (i&3)+8*(i>>2)+4*(lane>>5); canonical lanes 0 and 32 hold 16 each.
    float wsum = 0.0f;
#pragma unroll
    for (int i = 0; i < 16; ++i) {
        const int row = (i & 3) + 8 * (i >> 2) + 4 * (lane >> 5);  // < 32
        const float p2r = __shfl(p2, row);        // p2[lane r] = row r's |q|^2
        if (l31 == 0) wsum += sqrtf(fmaxf(racc0[i] + p2r, 0.0f));
    }
    wsum += __shfl_xor(wsum, 32);                 // combine lanes 0 and 32
    if (lane == 0) swsum[wave] = wsum;
    __syncthreads();

    if (tid == 0) {
        float total = 0.0f;
#pragma unroll
        for (int w = 0; w < WAVES; ++w) total += swsum[w];
        atomicAdd(out, total * (1.0f / (float)NPER));
    }
}

extern "C" void kernel_launch(void* const* d_in, const int* in_sizes, int n_in,
                              void* d_out, int out_size, void* d_ws, size_t ws_size,
                              hipStream_t stream) {
    const float* pred = (const float*)d_in[0];
    const float* gt   = (const float*)d_in[1];

    hipMemsetAsync(d_out, 0, sizeof(float), stream);

    dim3 grid(NPTS / BROWS, 1, 2 * BATCH);
    chamfer_mfma_kernel<<<grid, BLOCK, 0, stream>>>(pred, gt, (float*)d_out);
}

// Round 19
// 21.614 us; speedup vs baseline: 4.2203x; 1.1953x over previous
//
#include <hip/hip_runtime.h>
#include <hip/hip_fp16.h>

#define BATCH 8
#define NPTS  4096
#define NPER  32768           // BATCH*NPTS per cloud
#define NQTOT (2 * NPER)      // 65536 query slots (both passes)
#define WROWS 32              // query rows per wave (MFMA M)
#define WAVES 8
#define BLOCK (WAVES * 64)    // 512 threads
#define BROWS (WROWS * WAVES) // 256 rows per block
#define HALFT 2048            // targets per block (2-way target split)
#define TILES (HALFT / 32)    // 64 tiles of 32

typedef _Float16 half8  __attribute__((ext_vector_type(8)));
typedef float    f32x16 __attribute__((ext_vector_type(16)));

// ws layout: float partial[2][65536] : per-target-half min d2 (512 KB)

// K1: grid (16, 2, 16) = 512 blocks x 512 thr (8 waves) -> 2 blocks/CU,
// 4 waves/SIMD. Identical math to R18 (validated): one mfma_f32_32x32x16_f16
// per 32x32 tile, A masked to lanes<32 so B needs no masking; 2 tiles in
// flight + 1-iter LDS prefetch; 1 v_min per pair. Each block covers 256 rows
// x 2048 targets (its half), writes partial d2 = max(minscore + p2, 0)
// (monotonicity => cross-half min commutes). One thread zeroes out[0].
__global__ __launch_bounds__(BLOCK) void chamfer_mfma_kernel(
    const float* __restrict__ pred, const float* __restrict__ gt,
    float* __restrict__ partial, float* __restrict__ out)
{
    const int z    = blockIdx.z;                  // pass*8 + b
    const int b    = z & 7;
    const int pass = z >> 3;
    const int half = blockIdx.y;
    const float* query  = (pass ? gt : pred) + (size_t)b * NPTS * 3;
    const float* target = (pass ? pred : gt) + (size_t)b * NPTS * 3
                        + (size_t)half * HALFT * 3;

    __shared__ uint2 sT[HALFT];                   // 16 KB packed targets

    const int tid = threadIdx.x;

    if (blockIdx.x == 0 && half == 0 && z == 0 && tid == 0) out[0] = 0.0f;

    // ---- stage + convert this half's targets (4 per thread) ----
#pragma unroll
    for (int i = 0; i < HALFT / BLOCK; ++i) {
        const int t = tid + i * BLOCK;
        const float* tp = target + (size_t)t * 3;
        const __half hx = __float2half(tp[0]);
        const __half hy = __float2half(tp[1]);
        const __half hz = __float2half(tp[2]);
        const float fx = __half2float(hx), fy = __half2float(hy), fz = __half2float(hz);
        const __half hg = __float2half(fmaf(fx, fx, fmaf(fy, fy, fz * fz)));
        uint2 u;
        u.x = (unsigned)__half_as_ushort(hx) | ((unsigned)__half_as_ushort(hy) << 16);
        u.y = (unsigned)__half_as_ushort(hz) | ((unsigned)__half_as_ushort(hg) << 16);
        sT[t] = u;
    }

    const int lane = tid & 63;
    const int wave = tid >> 6;
    const int l31  = lane & 31;
    const int qrow0 = blockIdx.x * BROWS + wave * WROWS;
    const unsigned bm = (lane < 32) ? 0xFFFFFFFFu : 0u;   // low-half mask

    // ---- A fragment (+ per-lane p2 for query row l31) ----
    union { half8 h; unsigned u[4]; } A;
    A.u[2] = 0; A.u[3] = 0;
    float p2;
    {
        const float* qp = query + (size_t)(qrow0 + l31) * 3;
        const __half hx = __float2half(qp[0]);
        const __half hy = __float2half(qp[1]);
        const __half hz = __float2half(qp[2]);
        const float fx = __half2float(hx), fy = __half2float(hy), fz = __half2float(hz);
        p2 = fmaf(fx, fx, fmaf(fy, fy, fz * fz));
        const __half ax = __float2half(-2.0f * fx);   // exact (f16 in, x2 exp)
        const __half ay = __float2half(-2.0f * fy);
        const __half az = __float2half(-2.0f * fz);
        A.u[0] = ((unsigned)__half_as_ushort(ax) | ((unsigned)__half_as_ushort(ay) << 16)) & bm;
        A.u[1] = ((unsigned)__half_as_ushort(az) | (0x3C00u << 16)) & bm;  // (-2z, 1.0)
    }
    __syncthreads();

    // ---- main loop: 64 tiles of 32 targets, 2 in flight, prefetch 1 ahead ----
    f32x16 racc0, racc1, cz;
#pragma unroll
    for (int i = 0; i < 16; ++i) { racc0[i] = 3.0e38f; racc1[i] = 3.0e38f; cz[i] = 0.0f; }

    uint2 c0 = sT[l31];
    uint2 c1 = sT[32 + l31];
#pragma unroll 2
    for (int mt = 0; mt < TILES; mt += 2) {
        const int nx = (mt + 2) & (TILES - 1);
        const uint2 n0 = sT[nx * 32 + l31];           // prefetch next iter
        const uint2 n1 = sT[nx * 32 + 32 + l31];

        union { half8 h; unsigned u[4]; } B0, B1;     // raw, unmasked
        B0.u[0] = c0.x; B0.u[1] = c0.y; B0.u[2] = 0; B0.u[3] = 0;
        B1.u[0] = c1.x; B1.u[1] = c1.y; B1.u[2] = 0; B1.u[3] = 0;
        const f32x16 d0 = __builtin_amdgcn_mfma_f32_32x32x16_f16(A.h, B0.h, cz, 0, 0, 0);
        const f32x16 d1 = __builtin_amdgcn_mfma_f32_32x32x16_f16(A.h, B1.h, cz, 0, 0, 0);
#pragma unroll
        for (int i = 0; i < 16; ++i) {
            racc0[i] = fminf(racc0[i], d0[i]);
            racc1[i] = fminf(racc1[i], d1[i]);
        }
        c0 = n0; c1 = n1;
    }
#pragma unroll
    for (int i = 0; i < 16; ++i) racc0[i] = fminf(racc0[i], racc1[i]);

    // ---- min over 32 columns (shfl_xor stays within each 32-lane half) ----
#pragma unroll
    for (int i = 0; i < 16; ++i) {
        float v = racc0[i];
        v = fminf(v, __shfl_xor(v, 1));
        v = fminf(v, __shfl_xor(v, 2));
        v = fminf(v, __shfl_xor(v, 4));
        v = fminf(v, __shfl_xor(v, 8));
        v = fminf(v, __shfl_xor(v, 16));
        racc0[i] = v;
    }

    // ---- write partial d2 per row (lanes 0 and 32 hold 16 rows each) ----
    float* dst = partial + (size_t)half * NQTOT + (size_t)z * NPTS + qrow0;
#pragma unroll
    for (int i = 0; i < 16; ++i) {
        const int row = (i & 3) + 8 * (i >> 2) + 4 * (lane >> 5);  // < 32
        const float p2r = __shfl(p2, row);        // all lanes participate
        if (l31 == 0) {
            dst[row] = fmaxf(racc0[i] + p2r, 0.0f);
        }
    }
}

// K2: 64 blocks x 1024, one slot per thread: min over the 2 target halves,
// sqrt, deterministic LDS double tree-sum, one atomicAdd per block.
__global__ __launch_bounds__(1024) void reduce_kernel(
    const float* __restrict__ partial, float* __restrict__ out)
{
    const int tid = threadIdx.x;
    const int j   = blockIdx.x * 1024 + tid;      // 0..65535

    const float m = fminf(partial[j], partial[NQTOT + j]);
    __shared__ double sd[1024];
    sd[tid] = (double)sqrtf(m);
    __syncthreads();
    for (int off = 512; off > 0; off >>= 1) {
        if (tid < off) sd[tid] += sd[tid + off];
        __syncthreads();
    }
    if (tid == 0) atomicAdd(out, (float)(sd[0] / (double)NPER));
}

extern "C" void kernel_launch(void* const* d_in, const int* in_sizes, int n_in,
                              void* d_out, int out_size, void* d_ws, size_t ws_size,
                              hipStream_t stream) {
    const float* pred = (const float*)d_in[0];
    const float* gt   = (const float*)d_in[1];

    float* partial = (float*)d_ws;                // 512 KB

    dim3 grid(NPTS / BROWS, 2, 2 * BATCH);
    chamfer_mfma_kernel<<<grid, BLOCK, 0, stream>>>(pred, gt, partial, (float*)d_out);

    reduce_kernel<<<NQTOT / 1024, 1024, 0, stream>>>(partial, (float*)d_out);
}